// Round 11
// baseline (87.574 us; speedup 1.0000x reference)
//
#include <hip/hip_runtime.h>

#define S_PTS 4096            // sparse point count (fixed by problem)
#define TILE  2048            // points staged per LDS tile (32 KB)
#define NTILE (S_PTS / TILE)  // 2
#define LQ    32              // lanes cooperating per query
#define NQ    4               // queries per lane
#define QPB   32              // queries per block = (256/LQ)*NQ
#define RF    16              // shared-bound refresh cadence (iters)

// Full sorted top-3 insert. Strict '<' keeps incumbent on ties (same
// semantics as all passing rounds). No-op when d >= b2 -> safe to call
// with non-qualifying values.
__device__ __forceinline__ void insert3_full(float d, int s,
    float& b0, float& b1, float& b2, int& i0, int& i1, int& i2)
{
    const bool lt0 = d < b0, lt1 = d < b1, lt2 = d < b2;
    b2 = lt1 ? b1 : (lt2 ? d : b2);
    i2 = lt1 ? i1 : (lt2 ? s : i2);
    b1 = lt0 ? b0 : (lt1 ? d : b1);
    i1 = lt0 ? i0 : (lt1 ? s : i1);
    b0 = lt0 ? d : b0;
    i0 = lt0 ? s : i0;
}

// Finalize one query reading winner coords from GLOBAL (LDS tile is gone).
// Same dist/weight math as all passing kernels.
__device__ __forceinline__ void finalize_query_g(
    const float* __restrict__ sx, const float* __restrict__ fl,
    float* __restrict__ ob, int N, int n,
    float x0, float x1, float x2, int i0, int i1, int i2)
{
    const float ax = sx[i0], ay = sx[S_PTS + i0], az = sx[2 * S_PTS + i0];
    const float bx = sx[i1], by = sx[S_PTS + i1], bz = sx[2 * S_PTS + i1];
    const float cx = sx[i2], cy = sx[S_PTS + i2], cz = sx[2 * S_PTS + i2];

    float dx, dy, dz;
    dx = ax - x0; dy = ay - x1; dz = az - x2;
    const float dist0 = fmaxf(sqrtf(dx * dx + dy * dy + dz * dz), 1e-10f);
    dx = bx - x0; dy = by - x1; dz = bz - x2;
    const float dist1 = fmaxf(sqrtf(dx * dx + dy * dy + dz * dz), 1e-10f);
    dx = cx - x0; dy = cy - x1; dz = cz - x2;
    const float dist2 = fmaxf(sqrtf(dx * dx + dy * dy + dz * dz), 1e-10f);

    const float inv0 = 1.0f / dist0;
    const float inv1 = 1.0f / dist1;
    const float inv2 = 1.0f / dist2;
    const float wsum = (inv0 + inv1) + inv2;
    const float w0 = inv0 / wsum;
    const float w1 = inv1 / wsum;
    const float w2 = inv2 / wsum;

    #pragma unroll
    for (int c = 0; c < 3; ++c) {
        const float f0 = fl[c * S_PTS + i0];
        const float f1 = fl[c * S_PTS + i1];
        const float f2 = fl[c * S_PTS + i2];
        ob[c * N + n] = (w0 * f0 + w1 * f1) + w2 * f2;
    }
}

// 256 threads = 8 groups x 32 lanes; each lane owns NQ=4 queries.
// 32 queries/block, 32 KB LDS -> 4 blocks/CU, grid 1024 blocks.
__global__ __launch_bounds__(256, 4)
void upsample_flow_knn3(const float* __restrict__ xyz,         // [B,3,N]
                        const float* __restrict__ sparse_xyz,  // [B,3,S]
                        const float* __restrict__ sparse_flow, // [B,3,S]
                        float* __restrict__ out,               // [B,3,N]
                        int N, int blocks_per_batch)
{
    __shared__ float4 spt[TILE];  // (-2x, -2y, -2z, |s|^2) for current tile

    const int tid = threadIdx.x;
    const int b   = blockIdx.x / blocks_per_batch;
    const int qb  = blockIdx.x % blocks_per_batch;

    const float* sx = sparse_xyz + (size_t)b * 3 * S_PTS;

    const int g = tid >> 5;   // query group (0..7)
    const int j = tid & 31;   // scanner lane within group (0..31)

    // query q of this lane: n = qb*QPB + q*8 + g
    const float* xq = xyz + (size_t)b * 3 * N;
    float x0[NQ], x1[NQ], x2[NQ], qn[NQ];
    #pragma unroll
    for (int q = 0; q < NQ; ++q) {
        const int n = qb * QPB + q * 8 + g;
        x0[q] = xq[n];
        x1[q] = xq[N + n];
        x2[q] = xq[2 * N + n];
        qn[q] = __fadd_rn(
            __fadd_rn(__fmul_rn(x0[q], x0[q]), __fmul_rn(x1[q], x1[q])),
            __fmul_rn(x2[q], x2[q]));
    }

    float v0[NQ], v1[NQ], v2[NQ], S[NQ];
    int   i0[NQ], i1[NQ], i2[NQ];
    #pragma unroll
    for (int q = 0; q < NQ; ++q) {
        v0[q] = 3.4e38f; v1[q] = 3.4e38f; v2[q] = 3.4e38f;
        i0[q] = 0; i1[q] = 0; i2[q] = 0;
        S[q] = 3.4e38f;   // until first refresh: everything admitted
    }

    for (int t = 0; t < NTILE; ++t) {
        if (t) __syncthreads();  // previous tile fully consumed before overwrite

        // ---- stage tile t: (-2x,-2y,-2z, pinned |s|^2) into LDS ----
        // (x2 scaling is exact -> d2 below is bit-identical to reference form)
        const int sb = t * TILE;
        for (int i = tid; i < TILE; i += 256) {
            const float px = sx[sb + i];
            const float py = sx[S_PTS + sb + i];
            const float pz = sx[2 * S_PTS + sb + i];
            const float sn = __fadd_rn(
                __fadd_rn(__fmul_rn(px, px), __fmul_rn(py, py)),
                __fmul_rn(pz, pz));
            spt[i] = make_float4(-2.0f * px, -2.0f * py, -2.0f * pz, sn);
        }
        __syncthreads();

        // ---- scan in chunks of RF iters; refresh shared bound between ----
        for (int c = 0; c < (TILE / LQ) / RF; ++c) {
            #pragma unroll 4
            for (int ii = 0; ii < RF; ++ii) {
                const int sl = (((c * RF + ii) << 5) | j);
                const float4 p = spt[sl];
                const int s = sb + sl;
                #pragma unroll
                for (int q = 0; q < NQ; ++q) {
                    // tq = -2*dot (pinned, exact x2 scaling);
                    // d2 = (qn + tq) + sn == (qn - 2*dot) + sn bit-exactly
                    const float tq = __fadd_rn(
                        __fadd_rn(__fmul_rn(p.x, x0[q]), __fmul_rn(p.y, x1[q])),
                        __fmul_rn(p.z, x2[q]));
                    const float d2 = __fadd_rn(__fadd_rn(qn[q], tq), p.w);
                    // Prune: S[q] is an ACHIEVED 3rd-best across the group,
                    // so d2 > S[q] can never be in the final top-3. Ties kept
                    // (<=). Admitted non-qualifiers are no-ops in insert3_full.
                    if (d2 <= S[q])
                        insert3_full(d2, s, v0[q], v1[q], v2[q],
                                     i0[q], i1[q], i2[q]);
                }
            }
            // refresh: S = min over the group's 32 lanes of private b2
            #pragma unroll
            for (int q = 0; q < NQ; ++q) {
                float m = v2[q];
                #pragma unroll
                for (int mm = 1; mm <= 16; mm <<= 1)
                    m = fminf(m, __shfl_xor(m, mm, 64));
                S[q] = m;
            }
        }
    }

    // ---- merge the 32 partial top-3s per query (butterfly within group) ----
    #pragma unroll
    for (int m = 1; m <= 16; m <<= 1) {
        #pragma unroll
        for (int q = 0; q < NQ; ++q) {
            const float r0 = __shfl_xor(v0[q], m, 64);
            const float r1 = __shfl_xor(v1[q], m, 64);
            const float r2 = __shfl_xor(v2[q], m, 64);
            const int   k0 = __shfl_xor(i0[q], m, 64);
            const int   k1 = __shfl_xor(i1[q], m, 64);
            const int   k2 = __shfl_xor(i2[q], m, 64);
            insert3_full(r0, k0, v0[q], v1[q], v2[q], i0[q], i1[q], i2[q]);
            insert3_full(r1, k1, v0[q], v1[q], v2[q], i0[q], i1[q], i2[q]);
            insert3_full(r2, k2, v0[q], v1[q], v2[q], i0[q], i1[q], i2[q]);
        }
    }

    // ---- finalize the lane's 4 queries on lane j==0 (coords from global) ----
    if (j == 0) {
        const float* fl = sparse_flow + (size_t)b * 3 * S_PTS;
        float* ob = out + (size_t)b * 3 * N;
        #pragma unroll
        for (int q = 0; q < NQ; ++q) {
            const int n = qb * QPB + q * 8 + g;
            if (n < N)
                finalize_query_g(sx, fl, ob, N, n,
                                 x0[q], x1[q], x2[q], i0[q], i1[q], i2[q]);
        }
    }
}

extern "C" void kernel_launch(void* const* d_in, const int* in_sizes, int n_in,
                              void* d_out, int out_size, void* d_ws, size_t ws_size,
                              hipStream_t stream)
{
    const float* xyz         = (const float*)d_in[0];
    const float* sparse_xyz  = (const float*)d_in[1];
    const float* sparse_flow = (const float*)d_in[2];
    float* out = (float*)d_out;

    const int B = in_sizes[1] / (3 * S_PTS);          // 2
    const int N = in_sizes[0] / (3 * B);              // 16384
    const int blocks_per_batch = (N + QPB - 1) / QPB; // 512

    dim3 grid(B * blocks_per_batch);                  // 1024 blocks
    dim3 block(256);
    upsample_flow_knn3<<<grid, block, 0, stream>>>(
        xyz, sparse_xyz, sparse_flow, out, N, blocks_per_batch);
}

// Round 12
// 79.316 us; speedup vs baseline: 1.1041x; 1.1041x over previous
//
#include <hip/hip_runtime.h>

#define S_PTS 4096            // sparse point count (fixed by problem)
#define TILE  2048            // points staged per LDS tile (32 KB)
#define NTILE (S_PTS / TILE)  // 2
#define LQ    16              // lanes cooperating per query
#define NQ    2               // queries per lane
#define QPB   32              // queries per block = (256/LQ)*NQ

typedef float vf2 __attribute__((ext_vector_type(2)));

// Value-only top-3 insert: b0<=b1<=b2, 3 ops, branchless, no indices.
// (med3 update rule HW-validated in round 8: absmax unchanged.)
__device__ __forceinline__ void vins(float v, float& b0, float& b1, float& b2)
{
    const float n0 = fminf(b0, v);
    const float n1 = __builtin_amdgcn_fmed3f(b0, b1, v);
    const float n2 = __builtin_amdgcn_fmed3f(b1, b2, v);
    b0 = n0; b1 = n1; b2 = n2;
}

// Full sorted top-3 insert with indices. Strict '<' keeps incumbent on ties.
// No-op when d >= b2 -> safe with non-qualifying values.
__device__ __forceinline__ void insert3_full(float d, int s,
    float& b0, float& b1, float& b2, int& i0, int& i1, int& i2)
{
    const bool lt0 = d < b0, lt1 = d < b1, lt2 = d < b2;
    b2 = lt1 ? b1 : (lt2 ? d : b2);
    i2 = lt1 ? i1 : (lt2 ? s : i2);
    b1 = lt0 ? b0 : (lt1 ? d : b1);
    i1 = lt0 ? i0 : (lt1 ? s : i1);
    b0 = lt0 ? d : b0;
    i0 = lt0 ? s : i0;
}

// Finalize one query reading winner coords from GLOBAL (L2-resident).
// Same dist/weight math as all passing kernels.
__device__ __forceinline__ void finalize_query_g(
    const float* __restrict__ sx, const float* __restrict__ fl,
    float* __restrict__ ob, int N, int n,
    float x0, float x1, float x2, int i0, int i1, int i2)
{
    const float ax = sx[i0], ay = sx[S_PTS + i0], az = sx[2 * S_PTS + i0];
    const float bx = sx[i1], by = sx[S_PTS + i1], bz = sx[2 * S_PTS + i1];
    const float cx = sx[i2], cy = sx[S_PTS + i2], cz = sx[2 * S_PTS + i2];

    float dx, dy, dz;
    dx = ax - x0; dy = ay - x1; dz = az - x2;
    const float dist0 = fmaxf(sqrtf(dx * dx + dy * dy + dz * dz), 1e-10f);
    dx = bx - x0; dy = by - x1; dz = bz - x2;
    const float dist1 = fmaxf(sqrtf(dx * dx + dy * dy + dz * dz), 1e-10f);
    dx = cx - x0; dy = cy - x1; dz = cz - x2;
    const float dist2 = fmaxf(sqrtf(dx * dx + dy * dy + dz * dz), 1e-10f);

    const float inv0 = 1.0f / dist0;
    const float inv1 = 1.0f / dist1;
    const float inv2 = 1.0f / dist2;
    const float wsum = (inv0 + inv1) + inv2;
    const float w0 = inv0 / wsum;
    const float w1 = inv1 / wsum;
    const float w2 = inv2 / wsum;

    #pragma unroll
    for (int c = 0; c < 3; ++c) {
        const float f0 = fl[c * S_PTS + i0];
        const float f1 = fl[c * S_PTS + i1];
        const float f2 = fl[c * S_PTS + i2];
        ob[c * N + n] = (w0 * f0 + w1 * f1) + w2 * f2;
    }
}

// 256 threads = 16 groups x 16 lanes; each lane owns NQ=2 queries.
// 32 queries/block, 32 KB LDS -> 4 blocks/CU, grid 1024 blocks.
__global__ __launch_bounds__(256, 4)
void upsample_flow_knn3(const float* __restrict__ xyz,         // [B,3,N]
                        const float* __restrict__ sparse_xyz,  // [B,3,S]
                        const float* __restrict__ sparse_flow, // [B,3,S]
                        float* __restrict__ out,               // [B,3,N]
                        int N, int blocks_per_batch)
{
    __shared__ float4 spt[TILE];  // (-2x, -2y, -2z, |s|^2) for current tile

    const int tid = threadIdx.x;
    const int b   = blockIdx.x / blocks_per_batch;
    const int qb  = blockIdx.x % blocks_per_batch;

    const float* sx = sparse_xyz + (size_t)b * 3 * S_PTS;

    const int g = tid >> 4;   // query group (0..15)
    const int j = tid & 15;   // scanner lane within group (0..15)
    const int nA = qb * QPB + g;
    const int nB = nA + 16;

    const float* xq = xyz + (size_t)b * 3 * N;
    const float xA0 = xq[nA], xA1 = xq[N + nA], xA2 = xq[2 * N + nA];
    const float xB0 = xq[nB], xB1 = xq[N + nB], xB2 = xq[2 * N + nB];
    const float qnA = __fadd_rn(
        __fadd_rn(__fmul_rn(xA0, xA0), __fmul_rn(xA1, xA1)),
        __fmul_rn(xA2, xA2));
    const float qnB = __fadd_rn(
        __fadd_rn(__fmul_rn(xB0, xB0), __fmul_rn(xB1, xB1)),
        __fmul_rn(xB2, xB2));

    // packed per-lane query registers (lane-invariant within the group)
    vf2 X0, X1, X2, QN;
    X0.x = xA0; X0.y = xB0;
    X1.x = xA1; X1.y = xB1;
    X2.x = xA2; X2.y = xB2;
    QN.x = qnA; QN.y = qnB;

    // ================= PASS 1: exact top-3 VALUES (no indices) ============
    float a0 = 3.4e38f, a1 = 3.4e38f, a2 = 3.4e38f;   // query A bounds
    float c0 = 3.4e38f, c1 = 3.4e38f, c2 = 3.4e38f;   // query B bounds

    for (int t = 0; t < NTILE; ++t) {
        if (t) __syncthreads();  // previous tile fully consumed

        // stage tile t: (-2x,-2y,-2z, pinned |s|^2); x(-2) scaling is exact
        const int sb = t * TILE;
        for (int i = tid; i < TILE; i += 256) {
            const float px = sx[sb + i];
            const float py = sx[S_PTS + sb + i];
            const float pz = sx[2 * S_PTS + sb + i];
            const float sn = __fadd_rn(
                __fadd_rn(__fmul_rn(px, px), __fmul_rn(py, py)),
                __fmul_rn(pz, pz));
            spt[i] = make_float4(-2.0f * px, -2.0f * py, -2.0f * pz, sn);
        }
        __syncthreads();

        #pragma unroll 8
        for (int i = 0; i < TILE / LQ; ++i) {
            const float4 p = spt[(i << 4) | j];
            vf2 d2;
            {
                #pragma clang fp contract(off)
                // tq = -2*dot (exact); d2 = (qn + tq) + sn  == reference form
                const vf2 tq = (X0 * p.x + X1 * p.y) + X2 * p.z;
                d2 = (QN + tq) + p.w;
            }
            vins(d2.x, a0, a1, a2);
            vins(d2.y, c0, c1, c2);
        }
    }

    // merge bounds across the 16 lanes of the group (values only)
    #pragma unroll
    for (int m = 1; m <= 8; m <<= 1) {
        const float oa0 = __shfl_xor(a0, m, 64);
        const float oa1 = __shfl_xor(a1, m, 64);
        const float oa2 = __shfl_xor(a2, m, 64);
        vins(oa0, a0, a1, a2);
        vins(oa1, a0, a1, a2);
        vins(oa2, a0, a1, a2);
        const float oc0 = __shfl_xor(c0, m, 64);
        const float oc1 = __shfl_xor(c1, m, 64);
        const float oc2 = __shfl_xor(c2, m, 64);
        vins(oc0, c0, c1, c2);
        vins(oc1, c0, c1, c2);
        vins(oc2, c0, c1, c2);
    }
    const float SA = a2;   // exact final 3rd-best d2, query A
    const float SB = c2;   // exact final 3rd-best d2, query B

    // ========== PASS 2: index recovery, screened at the FINAL bound ========
    // Only true top-3 members (and exact ties) satisfy d2 <= S, so the
    // branch is taken ~9% of wave-iters. Extras inserted for the OTHER
    // query inside a taken branch have d2 > S >= all true members ->
    // they can never displace a true member in the merged top-3.
    float v0 = 3.4e38f, v1 = 3.4e38f, v2 = 3.4e38f;
    int   ia0 = 0, ia1 = 0, ia2 = 0;
    float w0 = 3.4e38f, w1 = 3.4e38f, w2 = 3.4e38f;
    int   ib0 = 0, ib1 = 0, ib2 = 0;

    // tile 1 is still resident in LDS: scan it first, then restage tile 0
    for (int tt = NTILE - 1; tt >= 0; --tt) {
        if (tt != NTILE - 1) {
            __syncthreads();  // all waves done reading previous tile
            const int sb = tt * TILE;
            for (int i = tid; i < TILE; i += 256) {
                const float px = sx[sb + i];
                const float py = sx[S_PTS + sb + i];
                const float pz = sx[2 * S_PTS + sb + i];
                const float sn = __fadd_rn(
                    __fadd_rn(__fmul_rn(px, px), __fmul_rn(py, py)),
                    __fmul_rn(pz, pz));
                spt[i] = make_float4(-2.0f * px, -2.0f * py, -2.0f * pz, sn);
            }
            __syncthreads();
        }
        const int sb = tt * TILE;

        #pragma unroll 4
        for (int i = 0; i < TILE / LQ; ++i) {
            const int sl = (i << 4) | j;
            const float4 p = spt[sl];
            vf2 d2;
            {
                #pragma clang fp contract(off)
                const vf2 tq = (X0 * p.x + X1 * p.y) + X2 * p.z;
                d2 = (QN + tq) + p.w;
            }
            if (d2.x <= SA || d2.y <= SB) {
                const int s = sb + sl;
                insert3_full(d2.x, s, v0, v1, v2, ia0, ia1, ia2);
                insert3_full(d2.y, s, w0, w1, w2, ib0, ib1, ib2);
            }
        }
    }

    // merge (value,index) triples across the group's 16 lanes
    #pragma unroll
    for (int m = 1; m <= 8; m <<= 1) {
        const float r0 = __shfl_xor(v0, m, 64);
        const float r1 = __shfl_xor(v1, m, 64);
        const float r2 = __shfl_xor(v2, m, 64);
        const int   k0 = __shfl_xor(ia0, m, 64);
        const int   k1 = __shfl_xor(ia1, m, 64);
        const int   k2 = __shfl_xor(ia2, m, 64);
        insert3_full(r0, k0, v0, v1, v2, ia0, ia1, ia2);
        insert3_full(r1, k1, v0, v1, v2, ia0, ia1, ia2);
        insert3_full(r2, k2, v0, v1, v2, ia0, ia1, ia2);

        const float s0 = __shfl_xor(w0, m, 64);
        const float s1 = __shfl_xor(w1, m, 64);
        const float s2 = __shfl_xor(w2, m, 64);
        const int   l0 = __shfl_xor(ib0, m, 64);
        const int   l1 = __shfl_xor(ib1, m, 64);
        const int   l2 = __shfl_xor(ib2, m, 64);
        insert3_full(s0, l0, w0, w1, w2, ib0, ib1, ib2);
        insert3_full(s1, l1, w0, w1, w2, ib0, ib1, ib2);
        insert3_full(s2, l2, w0, w1, w2, ib0, ib1, ib2);
    }

    // ---- finalize both queries on lane j==0 (coords from global/L2) ----
    if (j == 0) {
        const float* fl = sparse_flow + (size_t)b * 3 * S_PTS;
        float* ob = out + (size_t)b * 3 * N;
        if (nA < N)
            finalize_query_g(sx, fl, ob, N, nA, xA0, xA1, xA2, ia0, ia1, ia2);
        if (nB < N)
            finalize_query_g(sx, fl, ob, N, nB, xB0, xB1, xB2, ib0, ib1, ib2);
    }
}

extern "C" void kernel_launch(void* const* d_in, const int* in_sizes, int n_in,
                              void* d_out, int out_size, void* d_ws, size_t ws_size,
                              hipStream_t stream)
{
    const float* xyz         = (const float*)d_in[0];
    const float* sparse_xyz  = (const float*)d_in[1];
    const float* sparse_flow = (const float*)d_in[2];
    float* out = (float*)d_out;

    const int B = in_sizes[1] / (3 * S_PTS);          // 2
    const int N = in_sizes[0] / (3 * B);              // 16384
    const int blocks_per_batch = (N + QPB - 1) / QPB; // 512

    dim3 grid(B * blocks_per_batch);                  // 1024 blocks
    dim3 block(256);
    upsample_flow_knn3<<<grid, block, 0, stream>>>(
        xyz, sparse_xyz, sparse_flow, out, N, blocks_per_batch);
}

// Round 13
// 73.031 us; speedup vs baseline: 1.1991x; 1.0861x over previous
//
#include <hip/hip_runtime.h>

#define S_PTS 4096            // sparse point count (fixed by problem)
#define TILE  1024            // points staged per LDS tile (16 KB)
#define NTILE (S_PTS / TILE)  // 4
#define LQ    32              // lanes cooperating per query
#define NQ    2               // queries per lane
#define QPB   16              // queries per block = (256/LQ)*NQ

typedef float vf2 __attribute__((ext_vector_type(2)));

// Guarded sorted top-3 insert: caller guarantees d < b2.
// Strict '<' keeps earliest index on ties (matches jax.lax.top_k).
__device__ __forceinline__ void insert3_hit(float d, int s,
    float& b0, float& b1, float& b2, int& i0, int& i1, int& i2)
{
    const bool lt0 = d < b0, lt1 = d < b1;
    b2 = lt1 ? b1 : d;
    i2 = lt1 ? i1 : s;
    b1 = lt0 ? b0 : (lt1 ? d : b1);
    i1 = lt0 ? i0 : (lt1 ? s : i1);
    b0 = lt0 ? d : b0;
    i0 = lt0 ? s : i0;
}

// Full sorted top-3 insert (for cross-lane merge where d may be >= b2).
__device__ __forceinline__ void insert3_full(float d, int s,
    float& b0, float& b1, float& b2, int& i0, int& i1, int& i2)
{
    const bool lt0 = d < b0, lt1 = d < b1, lt2 = d < b2;
    b2 = lt1 ? b1 : (lt2 ? d : b2);
    i2 = lt1 ? i1 : (lt2 ? s : i2);
    b1 = lt0 ? b0 : (lt1 ? d : b1);
    i1 = lt0 ? i0 : (lt1 ? s : i1);
    b0 = lt0 ? d : b0;
    i0 = lt0 ? s : i0;
}

// Finalize one query reading winner coords from GLOBAL (L2-resident).
// Same dist/weight math as all passing kernels.
__device__ __forceinline__ void finalize_query_g(
    const float* __restrict__ sx, const float* __restrict__ fl,
    float* __restrict__ ob, int N, int n,
    float x0, float x1, float x2, int i0, int i1, int i2)
{
    const float ax = sx[i0], ay = sx[S_PTS + i0], az = sx[2 * S_PTS + i0];
    const float bx = sx[i1], by = sx[S_PTS + i1], bz = sx[2 * S_PTS + i1];
    const float cx = sx[i2], cy = sx[S_PTS + i2], cz = sx[2 * S_PTS + i2];

    float dx, dy, dz;
    dx = ax - x0; dy = ay - x1; dz = az - x2;
    const float dist0 = fmaxf(sqrtf(dx * dx + dy * dy + dz * dz), 1e-10f);
    dx = bx - x0; dy = by - x1; dz = bz - x2;
    const float dist1 = fmaxf(sqrtf(dx * dx + dy * dy + dz * dz), 1e-10f);
    dx = cx - x0; dy = cy - x1; dz = cz - x2;
    const float dist2 = fmaxf(sqrtf(dx * dx + dy * dy + dz * dz), 1e-10f);

    const float inv0 = 1.0f / dist0;
    const float inv1 = 1.0f / dist1;
    const float inv2 = 1.0f / dist2;
    const float wsum = (inv0 + inv1) + inv2;
    const float w0 = inv0 / wsum;
    const float w1 = inv1 / wsum;
    const float w2 = inv2 / wsum;

    #pragma unroll
    for (int c = 0; c < 3; ++c) {
        const float f0 = fl[c * S_PTS + i0];
        const float f1 = fl[c * S_PTS + i1];
        const float f2 = fl[c * S_PTS + i2];
        ob[c * N + n] = (w0 * f0 + w1 * f1) + w2 * f2;
    }
}

// 256 threads = 8 groups x 32 lanes; each lane owns NQ=2 queries.
// 16 queries/block, 16 KB LDS -> 8 blocks/CU (32 waves/CU), grid 2048.
__global__ __launch_bounds__(256, 8)
void upsample_flow_knn3(const float* __restrict__ xyz,         // [B,3,N]
                        const float* __restrict__ sparse_xyz,  // [B,3,S]
                        const float* __restrict__ sparse_flow, // [B,3,S]
                        float* __restrict__ out,               // [B,3,N]
                        int N, int blocks_per_batch)
{
    __shared__ float4 spt[TILE];  // (-2x, -2y, -2z, |s|^2) for current tile

    const int tid = threadIdx.x;
    const int b   = blockIdx.x / blocks_per_batch;
    const int qb  = blockIdx.x % blocks_per_batch;

    const float* sx = sparse_xyz + (size_t)b * 3 * S_PTS;

    const int g = tid >> 5;   // query group (0..7)
    const int j = tid & 31;   // scanner lane within group (0..31)
    const int nA = qb * QPB + g;
    const int nB = nA + 8;

    const float* xq = xyz + (size_t)b * 3 * N;
    const float xA0 = xq[nA], xA1 = xq[N + nA], xA2 = xq[2 * N + nA];
    const float xB0 = xq[nB], xB1 = xq[N + nB], xB2 = xq[2 * N + nB];
    const float qnA = __fadd_rn(
        __fadd_rn(__fmul_rn(xA0, xA0), __fmul_rn(xA1, xA1)),
        __fmul_rn(xA2, xA2));
    const float qnB = __fadd_rn(
        __fadd_rn(__fmul_rn(xB0, xB0), __fmul_rn(xB1, xB1)),
        __fmul_rn(xB2, xB2));

    // packed query registers: .x = query A, .y = query B
    vf2 X0, X1, X2, QN;
    X0.x = xA0; X0.y = xB0;
    X1.x = xA1; X1.y = xB1;
    X2.x = xA2; X2.y = xB2;
    QN.x = qnA; QN.y = qnB;

    float a0 = 3.4e38f, a1 = 3.4e38f, a2 = 3.4e38f;
    int  ia0 = 0, ia1 = 0, ia2 = 0;
    float c0 = 3.4e38f, c1 = 3.4e38f, c2 = 3.4e38f;
    int  ib0 = 0, ib1 = 0, ib2 = 0;

    for (int t = 0; t < NTILE; ++t) {
        if (t) __syncthreads();  // previous tile fully consumed before overwrite

        // ---- stage tile t: (-2x,-2y,-2z, pinned |s|^2) into LDS ----
        // (x(-2) scaling is exact -> d2 below is bit-identical to ref form)
        const int sb = t * TILE;
        #pragma unroll
        for (int k = 0; k < TILE / 256; ++k) {
            const int i = k * 256 + tid;
            const float px = sx[sb + i];
            const float py = sx[S_PTS + sb + i];
            const float pz = sx[2 * S_PTS + sb + i];
            const float sn = __fadd_rn(
                __fadd_rn(__fmul_rn(px, px), __fmul_rn(py, py)),
                __fmul_rn(pz, pz));
            spt[i] = make_float4(-2.0f * px, -2.0f * py, -2.0f * pz, sn);
        }
        __syncthreads();

        // ---- scan: lane j handles sl = 32*i + j; one LDS read, 2 queries ----
        #pragma unroll 4
        for (int i = 0; i < TILE / LQ; ++i) {
            const int sl = (i << 5) | j;
            const float4 p = spt[sl];
            const int s = sb + sl;

            vf2 d2;
            {
                #pragma clang fp contract(off)
                // tq = -2*dot (exact prescale); d2 = (qn + tq) + sn
                // == (qn - 2*dot) + sn bit-exactly (reference op order).
                // v_pk_mul/add_f32 are IEEE-rn => identical to scalar _rn.
                const vf2 tq = (X0 * p.x + X1 * p.y) + X2 * p.z;
                d2 = (QN + tq) + p.w;
            }
            if (d2.x < a2)
                insert3_hit(d2.x, s, a0, a1, a2, ia0, ia1, ia2);
            if (d2.y < c2)
                insert3_hit(d2.y, s, c0, c1, c2, ib0, ib1, ib2);
        }
    }

    // ---- merge the 32 partial top-3s per query (butterfly within group) ----
    #pragma unroll
    for (int m = 1; m <= 16; m <<= 1) {
        const float ra0 = __shfl_xor(a0, m, 64);
        const float ra1 = __shfl_xor(a1, m, 64);
        const float ra2 = __shfl_xor(a2, m, 64);
        const int   ka0 = __shfl_xor(ia0, m, 64);
        const int   ka1 = __shfl_xor(ia1, m, 64);
        const int   ka2 = __shfl_xor(ia2, m, 64);
        insert3_full(ra0, ka0, a0, a1, a2, ia0, ia1, ia2);
        insert3_full(ra1, ka1, a0, a1, a2, ia0, ia1, ia2);
        insert3_full(ra2, ka2, a0, a1, a2, ia0, ia1, ia2);

        const float rb0 = __shfl_xor(c0, m, 64);
        const float rb1 = __shfl_xor(c1, m, 64);
        const float rb2 = __shfl_xor(c2, m, 64);
        const int   kb0 = __shfl_xor(ib0, m, 64);
        const int   kb1 = __shfl_xor(ib1, m, 64);
        const int   kb2 = __shfl_xor(ib2, m, 64);
        insert3_full(rb0, kb0, c0, c1, c2, ib0, ib1, ib2);
        insert3_full(rb1, kb1, c0, c1, c2, ib0, ib1, ib2);
        insert3_full(rb2, kb2, c0, c1, c2, ib0, ib1, ib2);
    }

    // ---- finalize both queries on lane j==0 (coords from global/L2) ----
    if (j == 0) {
        const float* fl = sparse_flow + (size_t)b * 3 * S_PTS;
        float* ob = out + (size_t)b * 3 * N;
        if (nA < N)
            finalize_query_g(sx, fl, ob, N, nA, xA0, xA1, xA2, ia0, ia1, ia2);
        if (nB < N)
            finalize_query_g(sx, fl, ob, N, nB, xB0, xB1, xB2, ib0, ib1, ib2);
    }
}

extern "C" void kernel_launch(void* const* d_in, const int* in_sizes, int n_in,
                              void* d_out, int out_size, void* d_ws, size_t ws_size,
                              hipStream_t stream)
{
    const float* xyz         = (const float*)d_in[0];
    const float* sparse_xyz  = (const float*)d_in[1];
    const float* sparse_flow = (const float*)d_in[2];
    float* out = (float*)d_out;

    const int B = in_sizes[1] / (3 * S_PTS);          // 2
    const int N = in_sizes[0] / (3 * B);              // 16384
    const int blocks_per_batch = (N + QPB - 1) / QPB; // 1024

    dim3 grid(B * blocks_per_batch);                  // 2048 blocks
    dim3 block(256);
    upsample_flow_knn3<<<grid, block, 0, stream>>>(
        xyz, sparse_xyz, sparse_flow, out, N, blocks_per_batch);
}

// Round 14
// 63.013 us; speedup vs baseline: 1.3898x; 1.1590x over previous
//
#include <hip/hip_runtime.h>

#define S_PTS 4096            // sparse point count (fixed by problem)
#define TILE  1024            // points per LDS tile (16 KB)
#define NTILE (S_PTS / TILE)  // 4
#define QPB   16              // queries per block (4 waves x 4 queries)
#define CAP   24              // candidate-list capacity per query

typedef float vf2 __attribute__((ext_vector_type(2)));

// Value-only top-3 insert: b0<=b1<=b2, 3 branchless ops (HW-validated R8/R12).
__device__ __forceinline__ void vins(float v, float& b0, float& b1, float& b2)
{
    const float n0 = fminf(b0, v);
    const float n1 = __builtin_amdgcn_fmed3f(b0, b1, v);
    const float n2 = __builtin_amdgcn_fmed3f(b1, b2, v);
    b0 = n0; b1 = n1; b2 = n2;
}

// Stable top-3 insert by lexicographic (d2, idx) — exactly jax.lax.top_k
// semantics (ties -> lower index first). Insertion-order independent.
__device__ __forceinline__ void insert3_stable(float d, int s,
    float& b0, float& b1, float& b2, int& i0, int& i1, int& i2)
{
    const bool l0 = (d < b0) || (d == b0 && s < i0);
    const bool l1 = (d < b1) || (d == b1 && s < i1);
    const bool l2 = (d < b2) || (d == b2 && s < i2);
    b2 = l1 ? b1 : (l2 ? d : b2);
    i2 = l1 ? i1 : (l2 ? s : i2);
    b1 = l0 ? b0 : (l1 ? d : b1);
    i1 = l0 ? i0 : (l1 ? s : i1);
    b0 = l0 ? d : b0;
    i0 = l0 ? s : i0;
}

// fma-form screen metric e = sn - 2*dot (qn omitted: per-query constant).
// Uses prescaled LDS tile (-2x,-2y,-2z,sn). Packed -> v_pk_fma_f32.
__device__ __forceinline__ vf2 emetric(const float4 p,
                                       const vf2 X0, const vf2 X1, const vf2 X2)
{
    const vf2 pw = {p.w, p.w};
    vf2 e = pw;
    e += X0 * (vf2){p.x, p.x};
    e += X1 * (vf2){p.y, p.y};
    e += X2 * (vf2){p.z, p.z};
    return e;  // contraction allowed: bound metric only, slack covers skew
}

// 256 threads = 4 waves; each wave owns 4 queries scanned by all 64 lanes.
// 16 queries/block, ~17.7 KB LDS -> 8 blocks/CU, grid 2048.
__global__ __launch_bounds__(256, 8)
void upsample_flow_knn3(const float* __restrict__ xyz,         // [B,3,N]
                        const float* __restrict__ sparse_xyz,  // [B,3,S]
                        const float* __restrict__ sparse_flow, // [B,3,S]
                        float* __restrict__ out,               // [B,3,N]
                        int N, int blocks_per_batch)
{
    __shared__ float4 spt[TILE];       // (-2x,-2y,-2z,|s|^2) current tile
    __shared__ int   cand[QPB][CAP];   // candidate indices per query
    __shared__ int   ccnt[QPB];

    const int tid = threadIdx.x;
    const int b   = blockIdx.x / blocks_per_batch;
    const int qb  = blockIdx.x % blocks_per_batch;

    const float* sx = sparse_xyz + (size_t)b * 3 * S_PTS;
    const float* xq = xyz + (size_t)b * 3 * N;

    if (tid < QPB) ccnt[tid] = 0;

    const int g = tid >> 6;   // wave id (0..3)
    const int j = tid & 63;   // lane

    // 4 queries per wave: n = qb*16 + g*4 + q  (all 64 lanes share them)
    float x0[4], x1[4], x2[4];
    #pragma unroll
    for (int q = 0; q < 4; ++q) {
        const int n = qb * QPB + g * 4 + q;
        x0[q] = xq[n];
        x1[q] = xq[N + n];
        x2[q] = xq[2 * N + n];
    }
    const vf2 X0a = {x0[0], x0[1]}, X1a = {x1[0], x1[1]}, X2a = {x2[0], x2[1]};
    const vf2 X0b = {x0[2], x0[3]}, X1b = {x1[2], x1[3]}, X2b = {x2[2], x2[3]};

    // ============ PASS 1: values-only top-3 of e (no indices) =============
    float t0[4], t1[4], t2[4];
    #pragma unroll
    for (int q = 0; q < 4; ++q) { t0[q] = 3.4e38f; t1[q] = 3.4e38f; t2[q] = 3.4e38f; }

    for (int t = 0; t < NTILE; ++t) {
        if (t) __syncthreads();  // previous tile fully consumed

        const int sb = t * TILE;
        #pragma unroll
        for (int k = 0; k < TILE / 256; ++k) {
            const int i = k * 256 + tid;
            const float px = sx[sb + i];
            const float py = sx[S_PTS + sb + i];
            const float pz = sx[2 * S_PTS + sb + i];
            const float sn = __fadd_rn(
                __fadd_rn(__fmul_rn(px, px), __fmul_rn(py, py)),
                __fmul_rn(pz, pz));
            spt[i] = make_float4(-2.0f * px, -2.0f * py, -2.0f * pz, sn);
        }
        __syncthreads();

        #pragma unroll 8
        for (int i = 0; i < TILE / 64; ++i) {
            const float4 p = spt[(i << 6) | j];
            const vf2 eA = emetric(p, X0a, X1a, X2a);
            const vf2 eB = emetric(p, X0b, X1b, X2b);
            vins(eA.x, t0[0], t1[0], t2[0]);
            vins(eA.y, t0[1], t1[1], t2[1]);
            vins(eB.x, t0[2], t1[2], t2[2]);
            vins(eB.y, t0[3], t1[3], t2[3]);
        }
    }

    // merge bounds across the wave's 64 lanes (values only)
    #pragma unroll
    for (int m = 1; m <= 32; m <<= 1) {
        #pragma unroll
        for (int q = 0; q < 4; ++q) {
            const float o0 = __shfl_xor(t0[q], m, 64);
            const float o1 = __shfl_xor(t1[q], m, 64);
            const float o2 = __shfl_xor(t2[q], m, 64);
            vins(o0, t0[q], t1[q], t2[q]);
            vins(o1, t0[q], t1[q], t2[q]);
            vins(o2, t0[q], t1[q], t2[q]);
        }
    }
    // slackened screen threshold: covers fma-vs-pinned + qn-interleave skew
    // (<= ~4e-5) with >20x margin; extra admits resolved exactly later.
    float S[4];
    #pragma unroll
    for (int q = 0; q < 4; ++q)
        S[q] = t2[q] + (1e-3f + 1e-4f * fabsf(t2[q]));

    // ============ PASS 2: harvest candidate indices (rare appends) =========
    // tile 3 still resident in LDS: scan order 3,0,1,2
    for (int c2 = 0; c2 < NTILE; ++c2) {
        const int tt = (NTILE - 1 + c2) % NTILE;
        if (c2) {
            __syncthreads();  // all waves done with previous tile
            const int sb = tt * TILE;
            #pragma unroll
            for (int k = 0; k < TILE / 256; ++k) {
                const int i = k * 256 + tid;
                const float px = sx[sb + i];
                const float py = sx[S_PTS + sb + i];
                const float pz = sx[2 * S_PTS + sb + i];
                const float sn = __fadd_rn(
                    __fadd_rn(__fmul_rn(px, px), __fmul_rn(py, py)),
                    __fmul_rn(pz, pz));
                spt[i] = make_float4(-2.0f * px, -2.0f * py, -2.0f * pz, sn);
            }
            __syncthreads();
        }
        const int sb = tt * TILE;

        #pragma unroll 4
        for (int i = 0; i < TILE / 64; ++i) {
            const int sl = (i << 6) | j;
            const float4 p = spt[sl];
            const vf2 eA = emetric(p, X0a, X1a, X2a);
            const vf2 eB = emetric(p, X0b, X1b, X2b);
            if (eA.x <= S[0] || eA.y <= S[1] || eB.x <= S[2] || eB.y <= S[3]) {
                const int s = sb + sl;
                if (eA.x <= S[0]) {
                    const int k = atomicAdd(&ccnt[g * 4 + 0], 1);
                    if (k < CAP) cand[g * 4 + 0][k] = s;
                }
                if (eA.y <= S[1]) {
                    const int k = atomicAdd(&ccnt[g * 4 + 1], 1);
                    if (k < CAP) cand[g * 4 + 1][k] = s;
                }
                if (eB.x <= S[2]) {
                    const int k = atomicAdd(&ccnt[g * 4 + 2], 1);
                    if (k < CAP) cand[g * 4 + 2][k] = s;
                }
                if (eB.y <= S[3]) {
                    const int k = atomicAdd(&ccnt[g * 4 + 3], 1);
                    if (k < CAP) cand[g * 4 + 3][k] = s;
                }
            }
        }
    }
    __syncthreads();

    // ======= EXACT SELECT + finalize: one thread per query (tid<16) ========
    if (tid < QPB) {
        const int n = qb * QPB + tid;
        if (n < N) {
            const float qx0 = xq[n], qx1 = xq[N + n], qx2 = xq[2 * N + n];
            const float qn = __fadd_rn(
                __fadd_rn(__fmul_rn(qx0, qx0), __fmul_rn(qx1, qx1)),
                __fmul_rn(qx2, qx2));

            float b0 = 3.4e38f, b1 = 3.4e38f, b2 = 3.4e38f;
            int   i0 = 0x7fffffff, i1 = 0x7fffffff, i2 = 0x7fffffff;
            const int cnt = min(ccnt[tid], CAP);
            for (int k = 0; k < cnt; ++k) {
                const int s = cand[tid][k];
                const float px = sx[s];
                const float py = sx[S_PTS + s];
                const float pz = sx[2 * S_PTS + s];
                const float sn = __fadd_rn(
                    __fadd_rn(__fmul_rn(px, px), __fmul_rn(py, py)),
                    __fmul_rn(pz, pz));
                // exact reference-rounded d2: (qn - 2*dot) + sn
                const float dot = __fadd_rn(
                    __fadd_rn(__fmul_rn(qx0, px), __fmul_rn(qx1, py)),
                    __fmul_rn(qx2, pz));
                const float d2 = __fadd_rn(
                    __fsub_rn(qn, __fmul_rn(2.0f, dot)), sn);
                insert3_stable(d2, s, b0, b1, b2, i0, i1, i2);
            }

            // weights from direct-diff norm (reference math), gather flow
            const float ax = sx[i0], ay = sx[S_PTS + i0], az = sx[2 * S_PTS + i0];
            const float bx = sx[i1], by = sx[S_PTS + i1], bz = sx[2 * S_PTS + i1];
            const float cx = sx[i2], cy = sx[S_PTS + i2], cz = sx[2 * S_PTS + i2];

            float dx, dy, dz;
            dx = ax - qx0; dy = ay - qx1; dz = az - qx2;
            const float dist0 = fmaxf(sqrtf(dx * dx + dy * dy + dz * dz), 1e-10f);
            dx = bx - qx0; dy = by - qx1; dz = bz - qx2;
            const float dist1 = fmaxf(sqrtf(dx * dx + dy * dy + dz * dz), 1e-10f);
            dx = cx - qx0; dy = cy - qx1; dz = cz - qx2;
            const float dist2 = fmaxf(sqrtf(dx * dx + dy * dy + dz * dz), 1e-10f);

            const float inv0 = 1.0f / dist0;
            const float inv1 = 1.0f / dist1;
            const float inv2 = 1.0f / dist2;
            const float wsum = (inv0 + inv1) + inv2;
            const float w0 = inv0 / wsum;
            const float w1 = inv1 / wsum;
            const float w2 = inv2 / wsum;

            const float* fl = sparse_flow + (size_t)b * 3 * S_PTS;
            float* ob = out + (size_t)b * 3 * N;
            #pragma unroll
            for (int c = 0; c < 3; ++c) {
                const float f0 = fl[c * S_PTS + i0];
                const float f1 = fl[c * S_PTS + i1];
                const float f2 = fl[c * S_PTS + i2];
                ob[c * N + n] = (w0 * f0 + w1 * f1) + w2 * f2;
            }
        }
    }
}

extern "C" void kernel_launch(void* const* d_in, const int* in_sizes, int n_in,
                              void* d_out, int out_size, void* d_ws, size_t ws_size,
                              hipStream_t stream)
{
    const float* xyz         = (const float*)d_in[0];
    const float* sparse_xyz  = (const float*)d_in[1];
    const float* sparse_flow = (const float*)d_in[2];
    float* out = (float*)d_out;

    const int B = in_sizes[1] / (3 * S_PTS);          // 2
    const int N = in_sizes[0] / (3 * B);              // 16384
    const int blocks_per_batch = (N + QPB - 1) / QPB; // 1024

    dim3 grid(B * blocks_per_batch);                  // 2048 blocks
    dim3 block(256);
    upsample_flow_knn3<<<grid, block, 0, stream>>>(
        xyz, sparse_xyz, sparse_flow, out, N, blocks_per_batch);
}